// Round 1
// baseline (630.203 us; speedup 1.0000x reference)
//
#include <hip/hip_runtime.h>

typedef __bf16 bf16x8 __attribute__((ext_vector_type(8)));
typedef __bf16 bf16x4 __attribute__((ext_vector_type(4)));
typedef float  f32x4  __attribute__((ext_vector_type(4)));

// Problem constants (from reference)
#define NB   2
#define SEQ  2048
#define NHQ  32
#define NHKV 8
#define HD   128
// scale * log2(e):  (1/sqrt(128)) * 1.4426950408889634
#define SCL2E 0.12753599963140488f

__global__ __launch_bounds__(256) void gqa_attn_fwd(
    const float* __restrict__ qg, const float* __restrict__ kg,
    const float* __restrict__ vg, float* __restrict__ og)
{
    // LDS: K tile (64 kv x 128 d, bf16, row-major, swizzled)
    //      V tile transposed (128 d x 64 kv, bf16, swizzled)
    //      P scratch per wave (16 q x 64 kv, bf16, swizzled)
    __shared__ __bf16 Kl[64 * 128];
    __shared__ __bf16 Vt[128 * 64];
    __shared__ __bf16 Pl[4 * 16 * 64];

    const int tid  = threadIdx.x;
    const int w    = tid >> 6;
    const int lane = tid & 63;
    const int l15  = lane & 15;
    const int g    = lane >> 4;

    const int qt = blockIdx.x;   // q tile (64 rows)
    const int hq = blockIdx.y;
    const int b  = blockIdx.z;
    const int qb = qt * 64;
    const int hkv = hq >> 2;     // GROUP = 4

    // ---------------- load Q fragments (wave owns rows qb+w*16 .. +15) -------
    // A-frag layout: row = lane&15, k(d) = 8*(lane>>4) + j  (+ kk*32)
    const int qr = qb + w * 16 + l15;
    const float* qp = qg + (((size_t)b * SEQ + qr) * NHQ + hq) * HD + g * 8;
    bf16x8 aq[4];
#pragma unroll
    for (int kk = 0; kk < 4; ++kk) {
        const float4 f0 = *(const float4*)(qp + kk * 32);
        const float4 f1 = *(const float4*)(qp + kk * 32 + 4);
        bf16x8 t = {(__bf16)f0.x, (__bf16)f0.y, (__bf16)f0.z, (__bf16)f0.w,
                    (__bf16)f1.x, (__bf16)f1.y, (__bf16)f1.z, (__bf16)f1.w};
        aq[kk] = t;
    }

    const f32x4 fzero = {0.f, 0.f, 0.f, 0.f};
    f32x4 acc[8];
#pragma unroll
    for (int i = 0; i < 8; ++i) acc[i] = fzero;
    float m[4] = {-1e30f, -1e30f, -1e30f, -1e30f};
    float l[4] = {0.f, 0.f, 0.f, 0.f};

    const float* kbase = kg + ((size_t)b * SEQ * NHKV + hkv) * HD;
    const float* vbase = vg + ((size_t)b * SEQ * NHKV + hkv) * HD;
    const int ntiles = qt + 1;

    for (int t = 0; t < ntiles; ++t) {
        const int kv0 = t * 64;
        __syncthreads();   // previous tile's LDS reads complete

        // ------------- stage K (row-major) ---------------------------------
        // thread t handles float4 f = tid + i*256 : row = f>>5, dq = (f&31)*4
#pragma unroll
        for (int i = 0; i < 8; ++i) {
            const int f   = tid + i * 256;
            const int row = f >> 5;
            const int dq  = (f & 31) * 4;
            const float4 kf = *(const float4*)(kbase + (size_t)(kv0 + row) * (NHKV * HD) + dq);
            bf16x4 kb = {(__bf16)kf.x, (__bf16)kf.y, (__bf16)kf.z, (__bf16)kf.w};
            *(bf16x4*)&Kl[(row * 128 + dq) ^ ((row & 7) << 3)] = kb;
        }
        // ------------- stage V transposed ----------------------------------
        // 4x4 blocks: bb = tid + j*256 : rowg = bb>>5 (kv/4), dqg = bb&31 (d/4)
#pragma unroll
        for (int j = 0; j < 2; ++j) {
            const int bb   = tid + j * 256;
            const int rowg = bb >> 5;
            const int dq   = (bb & 31) * 4;
            const float* vp = vbase + (size_t)(kv0 + rowg * 4) * (NHKV * HD) + dq;
            const float4 v0 = *(const float4*)(vp);
            const float4 v1 = *(const float4*)(vp + NHKV * HD);
            const float4 v2 = *(const float4*)(vp + 2 * NHKV * HD);
            const float4 v3 = *(const float4*)(vp + 3 * NHKV * HD);
            bf16x4 o0 = {(__bf16)v0.x, (__bf16)v1.x, (__bf16)v2.x, (__bf16)v3.x};
            bf16x4 o1 = {(__bf16)v0.y, (__bf16)v1.y, (__bf16)v2.y, (__bf16)v3.y};
            bf16x4 o2 = {(__bf16)v0.z, (__bf16)v1.z, (__bf16)v2.z, (__bf16)v3.z};
            bf16x4 o3 = {(__bf16)v0.w, (__bf16)v1.w, (__bf16)v2.w, (__bf16)v3.w};
            const int d0 = dq, d1 = dq + 1, d2 = dq + 2, d3 = dq + 3;
            *(bf16x4*)&Vt[(d0 * 64 + rowg * 4) ^ (((d0 ^ (d0 >> 2)) & 7) << 3)] = o0;
            *(bf16x4*)&Vt[(d1 * 64 + rowg * 4) ^ (((d1 ^ (d1 >> 2)) & 7) << 3)] = o1;
            *(bf16x4*)&Vt[(d2 * 64 + rowg * 4) ^ (((d2 ^ (d2 >> 2)) & 7) << 3)] = o2;
            *(bf16x4*)&Vt[(d3 * 64 + rowg * 4) ^ (((d3 ^ (d3 >> 2)) & 7) << 3)] = o3;
        }
        __syncthreads();

        // ------------- QK^T : S[16 q][64 kv] -------------------------------
        f32x4 sf[4];
#pragma unroll
        for (int c = 0; c < 4; ++c) {
            sf[c] = fzero;
#pragma unroll
            for (int kk = 0; kk < 4; ++kk) {
                const int row = c * 16 + l15;   // kv col as B "col"
                const bf16x8 bk = *(const bf16x8*)&Kl[(row * 128 + kk * 32 + g * 8) ^ ((row & 7) << 3)];
                sf[c] = __builtin_amdgcn_mfma_f32_16x16x32_bf16(aq[kk], bk, sf[c], 0, 0, 0);
            }
        }

        // ------------- online softmax --------------------------------------
        // lane holds S[row=g*4+r][col=c*16+l15]
        float e[4][4];
        const bool last = (t == ntiles - 1);
#pragma unroll
        for (int c = 0; c < 4; ++c)
#pragma unroll
            for (int r = 0; r < 4; ++r) {
                float x = sf[c][r] * SCL2E;
                if (last) {
                    const int kvc = kv0 + c * 16 + l15;
                    const int qrr = qb + w * 16 + g * 4 + r;
                    if (kvc > qrr) x = -1e30f;
                }
                e[c][r] = x;
            }
        float mt[4], alpha[4];
#pragma unroll
        for (int r = 0; r < 4; ++r) {
            float mx = fmaxf(fmaxf(e[0][r], e[1][r]), fmaxf(e[2][r], e[3][r]));
            mx = fmaxf(mx, __shfl_xor(mx, 1));
            mx = fmaxf(mx, __shfl_xor(mx, 2));
            mx = fmaxf(mx, __shfl_xor(mx, 4));
            mx = fmaxf(mx, __shfl_xor(mx, 8));
            const float mn = fmaxf(m[r], mx);
            alpha[r] = exp2f(m[r] - mn);
            m[r] = mn;
            mt[r] = mn;
        }
        float rs[4] = {0.f, 0.f, 0.f, 0.f};
#pragma unroll
        for (int c = 0; c < 4; ++c)
#pragma unroll
            for (int r = 0; r < 4; ++r) {
                const float p = exp2f(e[c][r] - mt[r]);
                e[c][r] = p;
                rs[r] += p;
            }
#pragma unroll
        for (int r = 0; r < 4; ++r) {
            float s = rs[r];
            s += __shfl_xor(s, 1);
            s += __shfl_xor(s, 2);
            s += __shfl_xor(s, 4);
            s += __shfl_xor(s, 8);
            l[r] = l[r] * alpha[r] + s;
#pragma unroll
            for (int dch = 0; dch < 8; ++dch) acc[dch][r] *= alpha[r];
        }

        // ------------- P -> per-wave LDS (bf16) ----------------------------
#pragma unroll
        for (int c = 0; c < 4; ++c)
#pragma unroll
            for (int r = 0; r < 4; ++r) {
                const int row = g * 4 + r;
                Pl[w * 1024 + ((row * 64 + c * 16 + l15) ^ ((row & 7) << 3))] = (__bf16)e[c][r];
            }
        __syncthreads();   // P visibility (wave-local would suffice; safe)

        // ------------- PV : acc += P[16x64] * V[64x128] --------------------
        bf16x8 pa[2];
#pragma unroll
        for (int kk = 0; kk < 2; ++kk)
            pa[kk] = *(const bf16x8*)&Pl[w * 1024 + ((l15 * 64 + kk * 32 + g * 8) ^ ((l15 & 7) << 3))];
#pragma unroll
        for (int dch = 0; dch < 8; ++dch) {
            const int d = dch * 16 + l15;
#pragma unroll
            for (int kk = 0; kk < 2; ++kk) {
                const bf16x8 bv = *(const bf16x8*)&Vt[(d * 64 + kk * 32 + g * 8) ^ (((d ^ (d >> 2)) & 7) << 3)];
                acc[dch] = __builtin_amdgcn_mfma_f32_16x16x32_bf16(pa[kk], bv, acc[dch], 0, 0, 0);
            }
        }
    }

    // ---------------- epilogue: out = acc / l -------------------------------
    float invl[4];
#pragma unroll
    for (int r = 0; r < 4; ++r) invl[r] = 1.0f / l[r];
#pragma unroll
    for (int dch = 0; dch < 8; ++dch)
#pragma unroll
        for (int r = 0; r < 4; ++r) {
            const int qrr = qb + w * 16 + g * 4 + r;
            og[(((size_t)b * SEQ + qrr) * NHQ + hq) * HD + dch * 16 + l15] = acc[dch][r] * invl[r];
        }
}

extern "C" void kernel_launch(void* const* d_in, const int* in_sizes, int n_in,
                              void* d_out, int out_size, void* d_ws, size_t ws_size,
                              hipStream_t stream) {
    const float* q = (const float*)d_in[0];
    const float* k = (const float*)d_in[1];
    const float* v = (const float*)d_in[2];
    float* out = (float*)d_out;
    dim3 grid(SEQ / 64, NHQ, NB);
    dim3 block(256);
    gqa_attn_fwd<<<grid, block, 0, stream>>>(q, k, v, out);
}

// Round 2
// 376.090 us; speedup vs baseline: 1.6757x; 1.6757x over previous
//
#include <hip/hip_runtime.h>

typedef __bf16 bf16x8 __attribute__((ext_vector_type(8)));
typedef __bf16 bf16x4 __attribute__((ext_vector_type(4)));
typedef float  f32x4  __attribute__((ext_vector_type(4)));

// Problem constants (from reference)
#define NB   2
#define SEQ  2048
#define NHQ  32
#define NHKV 8
#define HD   128
#define KVSTR (NHKV * HD)   // 1024 floats between consecutive kv rows
// scale * log2(e):  (1/sqrt(128)) * 1.4426950408889634
#define SCL2E 0.12753599963140488f

__global__ __launch_bounds__(256, 2) void gqa_attn_fwd(
    const float* __restrict__ qg, const float* __restrict__ kg,
    const float* __restrict__ vg, float* __restrict__ og)
{
    // LDS: K double-buffered (2 x 64kv x 128d bf16, swizzled)     32 KB
    //      V transposed single buffer (128d x 64kv bf16, swizzled) 16 KB
    //      P scratch per wave (16q x 64kv bf16, swizzled)           8 KB
    __shared__ __bf16 Kl[2][64 * 128];
    __shared__ __bf16 Vt[128 * 64];
    __shared__ __bf16 Pl[4][16 * 64];

    const int tid  = threadIdx.x;
    const int w    = tid >> 6;
    const int lane = tid & 63;
    const int l15  = lane & 15;
    const int g    = lane >> 4;

    // big q-tiles first: smooths the causal load-imbalance tail
    const int qt = (SEQ / 64 - 1) - blockIdx.x;
    const int hq = blockIdx.y;
    const int b  = blockIdx.z;
    const int qb = qt * 64;
    const int hkv = hq >> 2;     // GROUP = 4

    const float* kbase = kg + ((size_t)b * SEQ * NHKV + hkv) * HD;
    const float* vbase = vg + ((size_t)b * SEQ * NHKV + hkv) * HD;
    const int ntiles = qt + 1;

    // ---------------- load Q fragments (wave owns rows qb+w*16 .. +15) -----
    // A-frag layout: row = lane&15, k(d) = 8*(lane>>4) + j  (+ kk*32)
    const int qr = qb + w * 16 + l15;
    const float* qp = qg + (((size_t)b * SEQ + qr) * NHQ + hq) * HD + g * 8;
    bf16x8 aq[4];
#pragma unroll
    for (int kk = 0; kk < 4; ++kk) {
        const float4 f0 = *(const float4*)(qp + kk * 32);
        const float4 f1 = *(const float4*)(qp + kk * 32 + 4);
        bf16x8 t = {(__bf16)f0.x, (__bf16)f0.y, (__bf16)f0.z, (__bf16)f0.w,
                    (__bf16)f1.x, (__bf16)f1.y, (__bf16)f1.z, (__bf16)f1.w};
        aq[kk] = t;
    }

    // ---------------- staging helpers (register-staged, T14) ----------------
    auto loadK = [&](int t, float4 kr[8]) {
#pragma unroll
        for (int i = 0; i < 8; ++i) {
            const int f = tid + i * 256;
            kr[i] = *(const float4*)(kbase + (size_t)(t * 64 + (f >> 5)) * KVSTR + (f & 31) * 4);
        }
    };
    auto storeK = [&](int buf, const float4 kr[8]) {
#pragma unroll
        for (int i = 0; i < 8; ++i) {
            const int f = tid + i * 256;
            const int row = f >> 5, dq = (f & 31) * 4;
            bf16x4 kb = {(__bf16)kr[i].x, (__bf16)kr[i].y, (__bf16)kr[i].z, (__bf16)kr[i].w};
            *(bf16x4*)&Kl[buf][(row * 128 + dq) ^ ((row & 7) << 3)] = kb;
        }
    };
    auto loadV = [&](int t, float4 vr[8]) {
#pragma unroll
        for (int j = 0; j < 2; ++j) {
            const int bb = tid + j * 256;
            const int rowg = bb >> 5, dq = (bb & 31) * 4;
            const float* vp = vbase + (size_t)(t * 64 + rowg * 4) * KVSTR + dq;
            vr[j * 4 + 0] = *(const float4*)(vp);
            vr[j * 4 + 1] = *(const float4*)(vp + KVSTR);
            vr[j * 4 + 2] = *(const float4*)(vp + 2 * KVSTR);
            vr[j * 4 + 3] = *(const float4*)(vp + 3 * KVSTR);
        }
    };
    auto storeV = [&](const float4 vr[8]) {
#pragma unroll
        for (int j = 0; j < 2; ++j) {
            const int bb = tid + j * 256;
            const int rowg = bb >> 5, dq = (bb & 31) * 4;
            const float4 v0 = vr[j * 4 + 0], v1 = vr[j * 4 + 1];
            const float4 v2 = vr[j * 4 + 2], v3 = vr[j * 4 + 3];
            bf16x4 o0 = {(__bf16)v0.x, (__bf16)v1.x, (__bf16)v2.x, (__bf16)v3.x};
            bf16x4 o1 = {(__bf16)v0.y, (__bf16)v1.y, (__bf16)v2.y, (__bf16)v3.y};
            bf16x4 o2 = {(__bf16)v0.z, (__bf16)v1.z, (__bf16)v2.z, (__bf16)v3.z};
            bf16x4 o3 = {(__bf16)v0.w, (__bf16)v1.w, (__bf16)v2.w, (__bf16)v3.w};
            const int d0 = dq, d1 = dq + 1, d2 = dq + 2, d3 = dq + 3;
            *(bf16x4*)&Vt[(d0 * 64 + rowg * 4) ^ (((d0 ^ (d0 >> 2)) & 7) << 3)] = o0;
            *(bf16x4*)&Vt[(d1 * 64 + rowg * 4) ^ (((d1 ^ (d1 >> 2)) & 7) << 3)] = o1;
            *(bf16x4*)&Vt[(d2 * 64 + rowg * 4) ^ (((d2 ^ (d2 >> 2)) & 7) << 3)] = o2;
            *(bf16x4*)&Vt[(d3 * 64 + rowg * 4) ^ (((d3 ^ (d3 >> 2)) & 7) << 3)] = o3;
        }
    };

    const f32x4 fzero = {0.f, 0.f, 0.f, 0.f};
    f32x4 acc[8];
#pragma unroll
    for (int i = 0; i < 8; ++i) acc[i] = fzero;
    float m[4] = {-1e30f, -1e30f, -1e30f, -1e30f};
    float l[4] = {0.f, 0.f, 0.f, 0.f};

    // ---------------- prologue: stage K(0) into buffer 0 --------------------
    {
        float4 kr[8];
        loadK(0, kr);
        storeK(0, kr);
    }

    for (int t = 0; t < ntiles; ++t) {
        const int cur = t & 1;
        const bool pf = (t + 1 < ntiles);   // block-uniform
        __syncthreads();   // all waves done: QK^T(t-1) [Kl alt], PV(t-1) [Vt]

        // ------------- issue next-tile global loads early (T14) ------------
        float4 kr[8], vr[8];
        if (pf) loadK(t + 1, kr);
        loadV(t, vr);

        // ------------- QK^T : S[16 q][64 kv] from Kl[cur] ------------------
        f32x4 sf[4];
        __builtin_amdgcn_s_setprio(1);
#pragma unroll
        for (int c = 0; c < 4; ++c) {
            sf[c] = fzero;
#pragma unroll
            for (int kk = 0; kk < 4; ++kk) {
                const int row = c * 16 + l15;   // kv index as B "col"
                const bf16x8 bk = *(const bf16x8*)&Kl[cur][(row * 128 + kk * 32 + g * 8) ^ ((row & 7) << 3)];
                sf[c] = __builtin_amdgcn_mfma_f32_16x16x32_bf16(aq[kk], bk, sf[c], 0, 0, 0);
            }
        }
        __builtin_amdgcn_s_setprio(0);

        // ------------- online softmax --------------------------------------
        // lane holds S[row=g*4+r][col=c*16+l15]
        float e[4][4];
        const bool last = (t == ntiles - 1);
#pragma unroll
        for (int c = 0; c < 4; ++c)
#pragma unroll
            for (int r = 0; r < 4; ++r) {
                float x = sf[c][r] * SCL2E;
                if (last) {
                    const int kvc = t * 64 + c * 16 + l15;
                    const int qrr = qb + w * 16 + g * 4 + r;
                    if (kvc > qrr) x = -1e30f;
                }
                e[c][r] = x;
            }
        float mt[4], alpha[4];
#pragma unroll
        for (int r = 0; r < 4; ++r) {
            float mx = fmaxf(fmaxf(e[0][r], e[1][r]), fmaxf(e[2][r], e[3][r]));
            mx = fmaxf(mx, __shfl_xor(mx, 1));
            mx = fmaxf(mx, __shfl_xor(mx, 2));
            mx = fmaxf(mx, __shfl_xor(mx, 4));
            mx = fmaxf(mx, __shfl_xor(mx, 8));
            const float mn = fmaxf(m[r], mx);
            alpha[r] = exp2f(m[r] - mn);
            m[r] = mn;
            mt[r] = mn;
        }
        float rs[4] = {0.f, 0.f, 0.f, 0.f};
#pragma unroll
        for (int c = 0; c < 4; ++c)
#pragma unroll
            for (int r = 0; r < 4; ++r) {
                const float p = exp2f(e[c][r] - mt[r]);
                e[c][r] = p;
                rs[r] += p;
            }
#pragma unroll
        for (int r = 0; r < 4; ++r) {
            float s = rs[r];
            s += __shfl_xor(s, 1);
            s += __shfl_xor(s, 2);
            s += __shfl_xor(s, 4);
            s += __shfl_xor(s, 8);
            l[r] = l[r] * alpha[r] + s;
#pragma unroll
            for (int dch = 0; dch < 8; ++dch) acc[dch][r] *= alpha[r];
        }

        // ------------- late LDS writes of the staged tiles -----------------
        storeV(vr);                       // V(t) -> Vt (read after bar2)
        if (pf) storeK(cur ^ 1, kr);      // K(t+1) -> alt buffer

        // ------------- P -> per-wave LDS (bf16) ----------------------------
#pragma unroll
        for (int c = 0; c < 4; ++c)
#pragma unroll
            for (int r = 0; r < 4; ++r) {
                const int row = g * 4 + r;
                Pl[w][(row * 64 + c * 16 + l15) ^ ((row & 7) << 3)] = (__bf16)e[c][r];
            }
        __syncthreads();   // Vt visible to all waves (and Pl write->read order)

        // ------------- PV : acc += P[16x64] * V(t)[64x128] -----------------
        bf16x8 pa[2];
#pragma unroll
        for (int kk = 0; kk < 2; ++kk)
            pa[kk] = *(const bf16x8*)&Pl[w][(l15 * 64 + kk * 32 + g * 8) ^ ((l15 & 7) << 3)];
        __builtin_amdgcn_s_setprio(1);
#pragma unroll
        for (int dch = 0; dch < 8; ++dch) {
            const int d = dch * 16 + l15;
#pragma unroll
            for (int kk = 0; kk < 2; ++kk) {
                const bf16x8 bv = *(const bf16x8*)&Vt[(d * 64 + kk * 32 + g * 8) ^ (((d ^ (d >> 2)) & 7) << 3)];
                acc[dch] = __builtin_amdgcn_mfma_f32_16x16x32_bf16(pa[kk], bv, acc[dch], 0, 0, 0);
            }
        }
        __builtin_amdgcn_s_setprio(0);
    }

    // ---------------- epilogue: out = acc / l -------------------------------
    float invl[4];
#pragma unroll
    for (int r = 0; r < 4; ++r) invl[r] = 1.0f / l[r];
#pragma unroll
    for (int dch = 0; dch < 8; ++dch)
#pragma unroll
        for (int r = 0; r < 4; ++r) {
            const int qrr = qb + w * 16 + g * 4 + r;
            og[(((size_t)b * SEQ + qrr) * NHQ + hq) * HD + dch * 16 + l15] = acc[dch][r] * invl[r];
        }
}

extern "C" void kernel_launch(void* const* d_in, const int* in_sizes, int n_in,
                              void* d_out, int out_size, void* d_ws, size_t ws_size,
                              hipStream_t stream) {
    const float* q = (const float*)d_in[0];
    const float* k = (const float*)d_in[1];
    const float* v = (const float*)d_in[2];
    float* out = (float*)d_out;
    dim3 grid(SEQ / 64, NHQ, NB);
    dim3 block(256);
    gqa_attn_fwd<<<grid, block, 0, stream>>>(q, k, v, out);
}

// Round 3
// 148.193 us; speedup vs baseline: 4.2526x; 2.5378x over previous
//
#include <hip/hip_runtime.h>

typedef __bf16 bf16x8 __attribute__((ext_vector_type(8)));
typedef __bf16 bf16x4 __attribute__((ext_vector_type(4)));
typedef float  f32x16 __attribute__((ext_vector_type(16)));
typedef unsigned int u32x4 __attribute__((ext_vector_type(4)));

#define NB   2
#define SEQ  2048
#define NHQ  32
#define NHKV 8
#define HD   128
#define KVSTR (NHKV * HD)          // 1024 floats between consecutive kv rows
#define SCL2E 0.12753599963140488f // (1/sqrt(128)) * log2(e)

// pack two f32 -> one dword of 2 bf16 (lo, hi)
static __device__ inline unsigned pk2(float a, float b) {
    unsigned short ua = __builtin_bit_cast(unsigned short, (__bf16)a);
    unsigned short ub = __builtin_bit_cast(unsigned short, (__bf16)b);
    return (unsigned)ua | ((unsigned)ub << 16);
}

__global__ __launch_bounds__(512, 2) void gqa_attn_fwd(
    const float* __restrict__ qg, const float* __restrict__ kg,
    const float* __restrict__ vg, float* __restrict__ og)
{
    // K double-buffered 2 x [64 kv][128 d] bf16, swz elem ^= (row&15)<<3   32 KB
    // V transposed [128 d][64 kv] bf16,        swz elem ^= (d&7)<<3        16 KB
    __shared__ __align__(16) __bf16 Kl[2][64 * 128];
    __shared__ __align__(16) __bf16 Vt[128 * 64];

    const int tid = threadIdx.x;
    const int w   = tid >> 6;        // wave 0..7
    const int lane = tid & 63;
    const int l31 = lane & 31;
    const int hi  = lane >> 5;

    // 1-D grid, strictly descending tile count for tail balance
    const int bid = blockIdx.x;
    const int qt  = 7 - (bid >> 6);          // 0..7, big first
    const int sub = bid & 63;
    const int hq  = sub & 31;
    const int b   = sub >> 5;
    const int qb  = qt * 256;
    const int hkv = hq >> 2;                 // GROUP = 4

    const float* kbase = kg + ((size_t)b * SEQ * NHKV + hkv) * HD;
    const float* vbase = vg + ((size_t)b * SEQ * NHKV + hkv) * HD;
    const int ntiles = (qb >> 6) + 4;        // KV tiles of 64 covering qb+255
    const int Tw     = (qb >> 6) + (w >> 1) + 1;   // this wave's active tiles

    // ---- Q fragments: lane owns q-row qb+32w+l31; B-frag k = 8*hi + j ------
    const int qrow = qb + w * 32 + l31;
    const float* qp = qg + (((size_t)b * SEQ + qrow) * NHQ + hq) * HD;
    bf16x8 bq[8];
#pragma unroll
    for (int s = 0; s < 8; ++s) {
        const int d0 = s * 16 + hi * 8;
        const float4 f0 = *(const float4*)(qp + d0);
        const float4 f1 = *(const float4*)(qp + d0 + 4);
        bf16x8 t = {(__bf16)f0.x, (__bf16)f0.y, (__bf16)f0.z, (__bf16)f0.w,
                    (__bf16)f1.x, (__bf16)f1.y, (__bf16)f1.z, (__bf16)f1.w};
        bq[s] = t;
    }

    // ---- staging helpers (register-staged, T14) ----------------------------
    auto loadK = [&](int t, float4 kr[4]) {
#pragma unroll
        for (int i = 0; i < 4; ++i) {
            const int f = tid + i * 512;
            kr[i] = *(const float4*)(kbase + (size_t)(t * 64 + (f >> 5)) * KVSTR + (f & 31) * 4);
        }
    };
    auto storeK = [&](int buf, const float4 kr[4]) {
#pragma unroll
        for (int i = 0; i < 4; ++i) {
            const int f = tid + i * 512;
            const int row = f >> 5, dq = (f & 31) * 4;
            bf16x4 kb = {(__bf16)kr[i].x, (__bf16)kr[i].y, (__bf16)kr[i].z, (__bf16)kr[i].w};
            *(bf16x4*)&Kl[buf][(row * 128 + dq) ^ ((row & 15) << 3)] = kb;
        }
    };
    auto loadV = [&](int t, float4 vr[4]) {
        const int rowg = tid >> 5, dq = (tid & 31) * 4;
        const float* vp = vbase + (size_t)(t * 64 + rowg * 4) * KVSTR + dq;
#pragma unroll
        for (int j = 0; j < 4; ++j) vr[j] = *(const float4*)(vp + j * KVSTR);
    };
    auto storeV = [&](const float4 vr[4]) {
        const int rowg = tid >> 5, dq = (tid & 31) * 4;
#pragma unroll
        for (int c = 0; c < 4; ++c) {
            const int d = dq + c;
            const float x0 = (c == 0) ? vr[0].x : (c == 1) ? vr[0].y : (c == 2) ? vr[0].z : vr[0].w;
            const float x1 = (c == 0) ? vr[1].x : (c == 1) ? vr[1].y : (c == 2) ? vr[1].z : vr[1].w;
            const float x2 = (c == 0) ? vr[2].x : (c == 1) ? vr[2].y : (c == 2) ? vr[2].z : vr[2].w;
            const float x3 = (c == 0) ? vr[3].x : (c == 1) ? vr[3].y : (c == 2) ? vr[3].z : vr[3].w;
            bf16x4 o = {(__bf16)x0, (__bf16)x1, (__bf16)x2, (__bf16)x3};
            *(bf16x4*)&Vt[(d * 64 + rowg * 4) ^ ((d & 7) << 3)] = o;
        }
    };

    f32x16 acc[4] = {};      // acc[db]: O[q=crow(r,hi)][d=db*32+l31]
    float m_r = -1e30f, l_r = 0.f;

    { float4 kr[4]; loadK(0, kr); storeK(0, kr); }

    for (int t = 0; t < ntiles; ++t) {
        const int cur = t & 1;
        const bool pf = (t + 1 < ntiles);
        __syncthreads();                       // prev tile's LDS reads done

        float4 kr[4], vr[4];
        if (pf) loadK(t + 1, kr);              // issue early (T14)
        loadV(t, vr);

        const bool active = (t < Tw);          // wave-uniform causal skip
        bf16x8 pa[4];
        if (active) {
            // ---- swapped QK^T: S^T[kv][q], A=K, B=Q ------------------------
            f32x16 sf[2];
            __builtin_amdgcn_s_setprio(1);
#pragma unroll
            for (int kb = 0; kb < 2; ++kb) {
                sf[kb] = (f32x16)(0.f);
                const int krow = kb * 32 + l31;
#pragma unroll
                for (int s = 0; s < 8; ++s) {
                    const int d0 = s * 16 + hi * 8;
                    const bf16x8 ak = *(const bf16x8*)&Kl[cur][(krow * 128 + d0) ^ ((krow & 15) << 3)];
                    sf[kb] = __builtin_amdgcn_mfma_f32_32x32x16_bf16(ak, bq[s], sf[kb], 0, 0, 0);
                }
            }
            __builtin_amdgcn_s_setprio(0);

            // ---- softmax (lane owns full row for q=qrow) -------------------
            float p[2][16];
            const bool maskt = (t == Tw - 1);
#pragma unroll
            for (int kb = 0; kb < 2; ++kb)
#pragma unroll
                for (int r = 0; r < 16; ++r) {
                    float x = sf[kb][r] * SCL2E;
                    if (maskt) {
                        const int kvg = t * 64 + kb * 32 + ((r & 3) + ((r >> 2) << 3) + (hi << 2));
                        if (kvg > qrow) x = -1e30f;
                    }
                    p[kb][r] = x;
                }
            // row max: in-register tree + cross-half swap
            float q16[16];
#pragma unroll
            for (int r = 0; r < 16; ++r) q16[r] = fmaxf(p[0][r], p[1][r]);
#pragma unroll
            for (int r = 0; r < 8; ++r) q16[r] = fmaxf(q16[r], q16[r + 8]);
#pragma unroll
            for (int r = 0; r < 4; ++r) q16[r] = fmaxf(q16[r], q16[r + 4]);
            float pm = fmaxf(fmaxf(q16[0], q16[1]), fmaxf(q16[2], q16[3]));
            pm = fmaxf(pm, __shfl_xor(pm, 32));

            // T13 defer-rescale
            const bool need = __any(pm - m_r > 8.0f);
            if (need) {
                const float mn = fmaxf(m_r, pm);
                const float alpha = exp2f(m_r - mn);
                m_r = mn;
                l_r *= alpha;
#pragma unroll
                for (int r = 0; r < 16; ++r) {
                    const float ab = __shfl(alpha, (r & 3) + ((r >> 2) << 3) + (hi << 2));
#pragma unroll
                    for (int db = 0; db < 4; ++db) acc[db][r] *= ab;
                }
            }
            // exp + row sum
            float rs = 0.f;
#pragma unroll
            for (int kb = 0; kb < 2; ++kb)
#pragma unroll
                for (int r = 0; r < 16; ++r) {
                    const float e = exp2f(p[kb][r] - m_r);
                    p[kb][r] = e;
                }
            {
                float s16[16];
#pragma unroll
                for (int r = 0; r < 16; ++r) s16[r] = p[0][r] + p[1][r];
#pragma unroll
                for (int r = 0; r < 8; ++r) s16[r] += s16[r + 8];
#pragma unroll
                for (int r = 0; r < 4; ++r) s16[r] += s16[r + 4];
                rs = (s16[0] + s16[1]) + (s16[2] + s16[3]);
                rs += __shfl_xor(rs, 32);
            }
            l_r += rs;

            // ---- T12: P -> bf16 A-frags via pack + permlane32_swap ---------
#pragma unroll
            for (int ks = 0; ks < 4; ++ks) {
                const int kb = ks >> 1, c = (ks & 1) * 8;
                unsigned x0 = pk2(p[kb][c + 0], p[kb][c + 1]);
                unsigned x1 = pk2(p[kb][c + 2], p[kb][c + 3]);
                unsigned y0 = pk2(p[kb][c + 4], p[kb][c + 5]);
                unsigned y1 = pk2(p[kb][c + 6], p[kb][c + 7]);
                asm volatile("v_permlane32_swap_b32 %0, %1" : "+v"(x0), "+v"(y0));
                asm volatile("v_permlane32_swap_b32 %0, %1" : "+v"(x1), "+v"(y1));
                u32x4 u = {x0, x1, y0, y1};
                pa[ks] = __builtin_bit_cast(bf16x8, u);
            }
        }

        // ---- late LDS writes of staged tiles -------------------------------
        storeV(vr);
        if (pf) storeK(cur ^ 1, kr);
        __syncthreads();                       // Vt(t), Kl[cur^1](t+1) ready

        if (active) {
            // ---- PV: acc[db] += P(32q x 16kv) * V(16kv x 32d) --------------
            __builtin_amdgcn_s_setprio(1);
#pragma unroll
            for (int db = 0; db < 4; ++db) {
                const int d = db * 32 + l31;
#pragma unroll
                for (int ks = 0; ks < 4; ++ks) {
                    const int kvo = ks * 16 + hi * 8;
                    const bf16x8 bv = *(const bf16x8*)&Vt[(d * 64 + kvo) ^ ((d & 7) << 3)];
                    acc[db] = __builtin_amdgcn_mfma_f32_32x32x16_bf16(pa[ks], bv, acc[db], 0, 0, 0);
                }
            }
            __builtin_amdgcn_s_setprio(0);
        }
    }

    // ---- epilogue: out = acc / l -------------------------------------------
    const float linv = 1.0f / l_r;
#pragma unroll
    for (int r = 0; r < 16; ++r) {
        const int crow = (r & 3) + ((r >> 2) << 3) + (hi << 2);
        const float lb = __shfl(linv, crow);
        const int qg_row = qb + w * 32 + crow;
        float* op = og + (((size_t)b * SEQ + qg_row) * NHQ + hq) * HD + l31;
#pragma unroll
        for (int db = 0; db < 4; ++db) op[db * 32] = acc[db][r] * lb;
    }
}

extern "C" void kernel_launch(void* const* d_in, const int* in_sizes, int n_in,
                              void* d_out, int out_size, void* d_ws, size_t ws_size,
                              hipStream_t stream) {
    const float* q = (const float*)d_in[0];
    const float* k = (const float*)d_in[1];
    const float* v = (const float*)d_in[2];
    float* out = (float*)d_out;
    dim3 grid((SEQ / 256) * NHQ * NB);   // 512 blocks, big-first
    dim3 block(512);
    gqa_attn_fwd<<<grid, block, 0, stream>>>(q, k, v, out);
}

// Round 4
// 138.719 us; speedup vs baseline: 4.5430x; 1.0683x over previous
//
#include <hip/hip_runtime.h>

typedef __bf16 bf16x8 __attribute__((ext_vector_type(8)));
typedef __bf16 bf16x4 __attribute__((ext_vector_type(4)));
typedef __bf16 bf16x2 __attribute__((ext_vector_type(2)));
typedef float  f32x16 __attribute__((ext_vector_type(16)));
typedef unsigned int u32x4 __attribute__((ext_vector_type(4)));

#define NB   2
#define SEQ  2048
#define NHQ  32
#define NHKV 8
#define HD   128
#define KVSTR (NHKV * HD)          // 1024 floats between consecutive kv rows
#define TSTEP (64 * KVSTR)         // floats between consecutive kv tiles
#define SCL2E 0.12753599963140488f // (1/sqrt(128)) * log2(e)

static __device__ inline unsigned pk2(float a, float b) {
    bf16x2 t = {(__bf16)a, (__bf16)b};
    return __builtin_bit_cast(unsigned, t);
}

__global__ __launch_bounds__(512, 2) void gqa_attn_fwd(
    const float* __restrict__ qg, const float* __restrict__ kg,
    const float* __restrict__ vg, float* __restrict__ og)
{
    // K: 2 x [64 kv][128 d] bf16, swz elem ^= (row&15)<<3           32 KB
    // V: 2 x [128 d][64 kv] bf16, swz elem ^= ((d>>2)&7)<<3         32 KB
    __shared__ __align__(16) __bf16 Kl[2][64 * 128];
    __shared__ __align__(16) __bf16 Vt[2][128 * 64];

    const int tid  = threadIdx.x;
    const int w    = tid >> 6;
    const int lane = tid & 63;
    const int l31  = lane & 31;
    const int hi   = lane >> 5;

    // complementary pairing: block c and c+256 sum to 36 staged tiles
    const int bid = blockIdx.x;
    const int qt  = (bid < 256) ? (7 - (bid >> 6)) : ((bid - 256) >> 6);
    const int sub = bid & 63;
    const int hq  = sub & 31;
    const int b   = sub >> 5;
    const int qb  = qt * 256;
    const int hkv = hq >> 2;

    const float* kbase = kg + ((size_t)b * SEQ * NHKV + hkv) * HD;
    const float* vbase = vg + ((size_t)b * SEQ * NHKV + hkv) * HD;
    const int ntiles = qt * 4 + 4;
    const int Tw     = qt * 4 + (w >> 1) + 1;    // this wave's active tiles

    // ---- Q fragments: lane owns q-row qb+32w+l31; B-frag k = 8*hi + j ------
    const int qrow = qb + w * 32 + l31;
    const float* qp = qg + (((size_t)b * SEQ + qrow) * NHQ + hq) * HD;
    bf16x8 bq[8];
#pragma unroll
    for (int s = 0; s < 8; ++s) {
        const int d0 = s * 16 + hi * 8;
        const float4 f0 = *(const float4*)(qp + d0);
        const float4 f1 = *(const float4*)(qp + d0 + 4);
        bf16x8 t = {(__bf16)f0.x, (__bf16)f0.y, (__bf16)f0.z, (__bf16)f0.w,
                    (__bf16)f1.x, (__bf16)f1.y, (__bf16)f1.z, (__bf16)f1.w};
        bq[s] = t;
    }

    // ---- staging: running pointers + per-thread constant offsets -----------
    const int krow0 = tid >> 5;            // 0..15  (K row base, +16i)
    const int kdq   = (tid & 31) * 4;      // 0..124
    const float* kp = kbase + (size_t)krow0 * KVSTR + kdq;     // tile 0
    const float* vp = vbase + (size_t)(tid >> 5) * 4 * KVSTR + kdq; // tile 0
    // K store: row&15 == krow0 -> lane-constant swizzle
    const int kout = krow0 * 128 + (kdq ^ (krow0 << 3));       // elem, +2048*i
    // V store: d = 4*(tid&31)+c -> (d>>2)&7 == tid&7 lane-constant
    const int vout = (4 * (tid & 31)) * 64 + (((tid >> 5) * 4) ^ ((tid & 7) << 3)); // +64*c

    auto loadK = [&](float4 kr[4]) {
#pragma unroll
        for (int i = 0; i < 4; ++i) kr[i] = *(const float4*)(kp + i * 16 * KVSTR);
        kp += TSTEP;
    };
    auto loadV = [&](float4 vr[4]) {
#pragma unroll
        for (int j = 0; j < 4; ++j) vr[j] = *(const float4*)(vp + j * KVSTR);
        vp += TSTEP;
    };
    auto storeK = [&](int buf, const float4 kr[4]) {
#pragma unroll
        for (int i = 0; i < 4; ++i) {
            bf16x4 kb4 = {(__bf16)kr[i].x, (__bf16)kr[i].y, (__bf16)kr[i].z, (__bf16)kr[i].w};
            *(bf16x4*)&Kl[buf][kout + i * 2048] = kb4;
        }
    };
    auto storeV = [&](int buf, const float4 vr[4]) {
#pragma unroll
        for (int c = 0; c < 4; ++c) {
            const float x0 = (c == 0) ? vr[0].x : (c == 1) ? vr[0].y : (c == 2) ? vr[0].z : vr[0].w;
            const float x1 = (c == 0) ? vr[1].x : (c == 1) ? vr[1].y : (c == 2) ? vr[1].z : vr[1].w;
            const float x2 = (c == 0) ? vr[2].x : (c == 1) ? vr[2].y : (c == 2) ? vr[2].z : vr[2].w;
            const float x3 = (c == 0) ? vr[3].x : (c == 1) ? vr[3].y : (c == 2) ? vr[3].z : vr[3].w;
            bf16x4 o = {(__bf16)x0, (__bf16)x1, (__bf16)x2, (__bf16)x3};
            *(bf16x4*)&Vt[buf][vout + c * 64] = o;
        }
    };

    f32x16 acc[4] = {};       // acc[db]: O[q=crow(r,hi)][d=db*32+l31]
    float m_r = -1e30f, l_r = 0.f;   // m_r in SCALED domain

    // ---- prologue: tile 0 -> LDS buf0; tile 1 -> regs ----------------------
    float4 kr[4], vr[4];
    loadK(kr); loadV(vr);
    storeK(0, kr); storeV(0, vr);
    if (ntiles > 1) { loadK(kr); loadV(vr); }

    // QK-read swizzle: krow&15 == l31&15 == l31 -> lane-constant
    const int swk = (l31 & 15) << 3;
    const int swv = (l31 >> 2) << 3;

    for (int t = 0; t < ntiles; ++t) {
        const int cur = t & 1;
        __syncthreads();      // prev iter reads of alt-buffers complete

        // ---- store tile t+1 (regs -> LDS alt), issue loads for t+2 ---------
        if (t + 1 < ntiles) { storeK(cur ^ 1, kr); storeV(cur ^ 1, vr); }
        if (t + 2 < ntiles) { loadK(kr); loadV(vr); }

        const bool active = (t < Tw);
        if (active) {
            // ---- swapped QK^T: S^T[kv][q], A=K, B=Q ------------------------
            f32x16 sf[2];
            __builtin_amdgcn_s_setprio(1);
#pragma unroll
            for (int kb = 0; kb < 2; ++kb) {
                sf[kb] = (f32x16)(0.f);
                const int krow = kb * 32 + l31;
#pragma unroll
                for (int s = 0; s < 8; ++s) {
                    const int d0 = s * 16 + hi * 8;
                    const bf16x8 ak = *(const bf16x8*)&Kl[cur][krow * 128 + (d0 ^ swk)];
                    sf[kb] = __builtin_amdgcn_mfma_f32_32x32x16_bf16(ak, bq[s], sf[kb], 0, 0, 0);
                }
            }
            __builtin_amdgcn_s_setprio(0);

            // ---- mask (raw domain), max tree, defer-rescale ----------------
            if (t == Tw - 1) {
#pragma unroll
                for (int kb = 0; kb < 2; ++kb)
#pragma unroll
                    for (int r = 0; r < 16; ++r) {
                        const int kvg = t * 64 + kb * 32 + ((r & 3) + ((r >> 2) << 3) + (hi << 2));
                        if (kvg > qrow) sf[kb][r] = -1e30f;
                    }
            }
            float t16[16];
#pragma unroll
            for (int r = 0; r < 16; ++r) t16[r] = fmaxf(sf[0][r], sf[1][r]);
#pragma unroll
            for (int r = 0; r < 8; ++r) t16[r] = fmaxf(t16[r], t16[r + 8]);
#pragma unroll
            for (int r = 0; r < 4; ++r) t16[r] = fmaxf(t16[r], t16[r + 4]);
            float pm = fmaxf(fmaxf(t16[0], t16[1]), fmaxf(t16[2], t16[3]));
            pm = fmaxf(pm, __shfl_xor(pm, 32));
            const float pms = pm * SCL2E;

            if (__any(pms - m_r > 8.0f)) {            // T13
                const float mn = fmaxf(m_r, pms);
                const float alpha = exp2f(m_r - mn);
                m_r = mn;
                l_r *= alpha;
#pragma unroll
                for (int r = 0; r < 16; ++r) {
                    const float ab = __shfl(alpha, (r & 3) + ((r >> 2) << 3) + (hi << 2));
#pragma unroll
                    for (int db = 0; db < 4; ++db) acc[db][r] *= ab;
                }
            }

            // ---- exp (scale folded into fma) + row sum ---------------------
            float p[2][16];
#pragma unroll
            for (int kb = 0; kb < 2; ++kb)
#pragma unroll
                for (int r = 0; r < 16; ++r)
                    p[kb][r] = exp2f(fmaf(sf[kb][r], SCL2E, -m_r));
            {
                float s16[16];
#pragma unroll
                for (int r = 0; r < 16; ++r) s16[r] = p[0][r] + p[1][r];
#pragma unroll
                for (int r = 0; r < 8; ++r) s16[r] += s16[r + 8];
#pragma unroll
                for (int r = 0; r < 4; ++r) s16[r] += s16[r + 4];
                float rs = (s16[0] + s16[1]) + (s16[2] + s16[3]);
                rs += __shfl_xor(rs, 32);
                l_r += rs;
            }

            // ---- T12: P -> bf16 A-frags via pack + permlane32_swap ---------
            bf16x8 pa[4];
#pragma unroll
            for (int ks = 0; ks < 4; ++ks) {
                const int kb = ks >> 1, c = (ks & 1) * 8;
                unsigned x0 = pk2(p[kb][c + 0], p[kb][c + 1]);
                unsigned x1 = pk2(p[kb][c + 2], p[kb][c + 3]);
                unsigned y0 = pk2(p[kb][c + 4], p[kb][c + 5]);
                unsigned y1 = pk2(p[kb][c + 6], p[kb][c + 7]);
                asm volatile("v_permlane32_swap_b32 %0, %1" : "+v"(x0), "+v"(y0));
                asm volatile("v_permlane32_swap_b32 %0, %1" : "+v"(x1), "+v"(y1));
                u32x4 u = {x0, x1, y0, y1};
                pa[ks] = __builtin_bit_cast(bf16x8, u);
            }

            // ---- PV: acc[db] += P(32q x 16kv) * V(16kv x 32d) --------------
            __builtin_amdgcn_s_setprio(1);
#pragma unroll
            for (int db = 0; db < 4; ++db) {
                const int dbase = (db * 32 + l31) * 64;
#pragma unroll
                for (int ks = 0; ks < 4; ++ks) {
                    const int kvo = ks * 16 + hi * 8;
                    const bf16x8 bv = *(const bf16x8*)&Vt[cur][dbase + (kvo ^ swv)];
                    acc[db] = __builtin_amdgcn_mfma_f32_32x32x16_bf16(pa[ks], bv, acc[db], 0, 0, 0);
                }
            }
            __builtin_amdgcn_s_setprio(0);
        }
    }

    // ---- epilogue: out = acc / l -------------------------------------------
    const float linv = 1.0f / l_r;
#pragma unroll
    for (int r = 0; r < 16; ++r) {
        const int crow = (r & 3) + ((r >> 2) << 3) + (hi << 2);
        const float lb = __shfl(linv, crow);
        const int qg_row = qb + w * 32 + crow;
        float* op = og + (((size_t)b * SEQ + qg_row) * NHQ + hq) * HD + l31;
#pragma unroll
        for (int db = 0; db < 4; ++db) op[db * 32] = acc[db][r] * lb;
    }
}

extern "C" void kernel_launch(void* const* d_in, const int* in_sizes, int n_in,
                              void* d_out, int out_size, void* d_ws, size_t ws_size,
                              hipStream_t stream) {
    const float* q = (const float*)d_in[0];
    const float* k = (const float*)d_in[1];
    const float* v = (const float*)d_in[2];
    float* out = (float*)d_out;
    dim3 grid((SEQ / 256) * NHQ * NB);   // 512 blocks, complementary pairing
    dim3 block(512);
    gqa_attn_fwd<<<grid, block, 0, stream>>>(q, k, v, out);
}